// Round 16
// baseline (220.112 us; speedup 1.0000x reference)
//
#include <hip/hip_runtime.h>
#include <hip/hip_bf16.h>
#include <hip/hip_fp16.h>

typedef _Float16 f16x8 __attribute__((ext_vector_type(8)));
typedef _Float16 f16x4 __attribute__((ext_vector_type(4)));
typedef float f32x4 __attribute__((ext_vector_type(4)));

typedef const __attribute__((address_space(1))) void gvoid_t;
typedef __attribute__((address_space(3))) void svoid_t;

constexpr int Bb = 4, Lq = 2056, Dd = 1024, NH = 16, HD = 64, NMEM = 8;
constexpr int Mtot = Bb * Lq;  // 8224
constexpr int KEYS = 128;      // keys per attention LDS tile (128 = 4 ks-subtiles)
constexpr int NT = (Lq + KEYS - 1) / KEYS;  // 17 key tiles
constexpr int NTQP = 17;       // paired q-tile blocks: px=0 -> {0}; px>=1 -> {33-px, px}
constexpr int LqV = 2064;      // padded vT column count (sigma of last 64-block in-bounds)

__device__ inline float fexp2(float x) {  // v_exp_f32 computes 2^x
  float r;
  asm("v_exp_f32 %0, %1" : "=v"(r) : "v"(x));
  return r;
}

// ---------- cast f32 -> f16 (n multiple of 8) ----------
__global__ __launch_bounds__(256) void cast_f16(const float* __restrict__ in,
                                                _Float16* __restrict__ out, int n8) {
  int i = blockIdx.x * blockDim.x + threadIdx.x;
  if (i >= n8) return;
  const float4* p = reinterpret_cast<const float4*>(in) + (size_t)i * 2;
  float4 a = p[0], b = p[1];
  f16x8 o;
  o[0] = (_Float16)a.x; o[1] = (_Float16)a.y; o[2] = (_Float16)a.z; o[3] = (_Float16)a.w;
  o[4] = (_Float16)b.x; o[5] = (_Float16)b.y; o[6] = (_Float16)b.z; o[7] = (_Float16)b.w;
  *(reinterpret_cast<f16x8*>(out) + i) = o;
}

// ---------- transpose + cast: in (rows x cols) f32 -> out (cols x rows) f16 ----------
__global__ void transpose_cast(const float* __restrict__ in, _Float16* __restrict__ out,
                               int rows, int cols) {
  __shared__ float t[32][33];
  int c0 = blockIdx.x * 32, r0 = blockIdx.y * 32;
  int tx = threadIdx.x, ty = threadIdx.y;
#pragma unroll
  for (int i = 0; i < 4; ++i)
    t[ty + i * 8][tx] = in[(size_t)(r0 + ty + i * 8) * cols + c0 + tx];
  __syncthreads();
#pragma unroll
  for (int i = 0; i < 4; ++i)
    out[(size_t)(c0 + ty + i * 8) * rows + r0 + tx] = (_Float16)t[tx][ty + i * 8];
}

// ---------- GEMM: C(MxN) = A(MxK) * Bt(NxK)^T, fp16 in, fp32 acc ----------
// (unchanged from R14 known-good)
template <int EPI>
__global__ __launch_bounds__(256) void gemm_f16(
    const _Float16* __restrict__ A, const _Float16* __restrict__ Bt,
    int M, int N, int Kd, float* __restrict__ Cf,
    _Float16* __restrict__ qout, _Float16* __restrict__ kout, _Float16* __restrict__ vtout) {
  constexpr int BM = 128, BN = 128, BK = 64;
  __shared__ _Float16 smem[2][2 * BM * BK];  // [dbuf][A tile | B tile] = 64 KB
  const int tid = threadIdx.x;
  const int wid = tid >> 6, lane = tid & 63;
  const int wr = wid >> 1, wc = wid & 1;
  const int l16 = lane & 15, lq = lane >> 4;

  const int gx = gridDim.x;
  const int nwg = gx * gridDim.y;
  const int i0 = blockIdx.y * gx + blockIdx.x;
  const int cpx = nwg >> 3;
  const int logical = (i0 & 7) * cpx + (i0 >> 3);
  const int m0 = (logical / gx) * BM, n0 = (logical % gx) * BN;

  f32x4 acc[4][4];
#pragma unroll
  for (int i = 0; i < 4; ++i)
#pragma unroll
    for (int j = 0; j < 4; ++j) acc[i][j] = (f32x4){0.f, 0.f, 0.f, 0.f};

  auto stage = [&](int sb, int kt) {
    const size_t kbase = (size_t)kt * BK;
    _Float16* sm = smem[sb];
#pragma unroll
    for (int c = 0; c < 4; ++c) {
      int q = wid * 256 + c * 64 + lane;
      int r = q >> 3, cc = q & 7;
      int gr = m0 + r; gr = gr < M ? gr : M - 1;
      const _Float16* src = A + (size_t)gr * Kd + kbase + ((cc ^ (r & 7)) << 3);
      __builtin_amdgcn_global_load_lds((gvoid_t*)src,
          (svoid_t*)(sm + (size_t)(wid * 256 + c * 64) * 8), 16, 0, 0);
    }
#pragma unroll
    for (int c = 0; c < 4; ++c) {
      int q = wid * 256 + c * 64 + lane;
      int r = q >> 3, cc = q & 7;
      const _Float16* src = Bt + (size_t)(n0 + r) * Kd + kbase + ((cc ^ (r & 7)) << 3);
      __builtin_amdgcn_global_load_lds((gvoid_t*)src,
          (svoid_t*)(sm + BM * BK + (size_t)(wid * 256 + c * 64) * 8), 16, 0, 0);
    }
  };

  const int KT = Kd / BK;
  stage(0, 0);
  __syncthreads();
  int sbuf = 0;
  for (int kt = 0; kt < KT; ++kt) {
    if (kt + 1 < KT) stage(sbuf ^ 1, kt + 1);  // prefetch overlaps compute
    const _Float16* sm = smem[sbuf];
#pragma unroll
    for (int kk = 0; kk < 2; ++kk) {
      f16x8 af[4], bfr[4];
#pragma unroll
      for (int i = 0; i < 4; ++i) {
        int r = wr * 64 + i * 16 + l16;
        int off = r * 64 + (((kk * 4 + lq) ^ (r & 7)) << 3);
        af[i] = *(const f16x8*)(sm + off);
      }
#pragma unroll
      for (int j = 0; j < 4; ++j) {
        int r = wc * 64 + j * 16 + l16;
        int off = BM * BK + r * 64 + (((kk * 4 + lq) ^ (r & 7)) << 3);
        bfr[j] = *(const f16x8*)(sm + off);
      }
#pragma unroll
      for (int i = 0; i < 4; ++i)
#pragma unroll
        for (int j = 0; j < 4; ++j)
          acc[i][j] = __builtin_amdgcn_mfma_f32_16x16x32_f16(af[i], bfr[j], acc[i][j], 0, 0, 0);
    }
    __syncthreads();
    sbuf ^= 1;
  }

  // epilogue: D row = (lane>>4)*4 + reg, col = lane&15
  if (EPI == 1 && n0 >= 2 * Dd) {
#pragma unroll
    for (int i = 0; i < 4; ++i) {
      int mb = m0 + wr * 64 + i * 16 + lq * 4;
      if (mb >= M) continue;
      int b = mb / Lq, l = mb - b * Lq;
#pragma unroll
      for (int j = 0; j < 4; ++j) {
        int n = n0 + wc * 64 + j * 16 + l16;
        int h = (n >> 6) & 15, d = n & 63;
        if (l + 4 <= Lq) {
          int kk = l & 63;
          int ks = kk >> 5, rem = kk & 31, half = rem >> 4, idx = rem & 15;
          int col = (l & ~63) + (ks * 4 + (idx >> 2)) * 8 + half * 4;  // idx&3 == 0
          f16x4 pk;
          pk[0] = (_Float16)acc[i][j][0]; pk[1] = (_Float16)acc[i][j][1];
          pk[2] = (_Float16)acc[i][j][2]; pk[3] = (_Float16)acc[i][j][3];
          *(f16x4*)(vtout + ((size_t)(b * NH + h) * HD + d) * LqV + col) = pk;
        } else {
#pragma unroll
          for (int r = 0; r < 4; ++r) {
            int m = mb + r;
            if (m >= M) continue;
            int b2 = m / Lq, l2 = m - b2 * Lq;
            int kk = l2 & 63;
            int ks = kk >> 5, rem = kk & 31, half = rem >> 4, idx = rem & 15;
            int col = (l2 & ~63) + (ks * 4 + (idx >> 2)) * 8 + half * 4 + (idx & 3);
            vtout[((size_t)(b2 * NH + h) * HD + d) * LqV + col] = (_Float16)acc[i][j][r];
          }
        }
      }
    }
  } else {
#pragma unroll
    for (int i = 0; i < 4; ++i) {
#pragma unroll
      for (int r = 0; r < 4; ++r) {
        int m = m0 + wr * 64 + i * 16 + lq * 4 + r;
        if (m >= M) continue;
        if (EPI == 0) {
#pragma unroll
          for (int j = 0; j < 4; ++j) {
            int n = n0 + wc * 64 + j * 16 + l16;
            Cf[(size_t)m * N + n] = acc[i][j][r];
          }
        } else {
          int b = m / Lq, l = m - b * Lq;
#pragma unroll
          for (int j = 0; j < 4; ++j) {
            int n = n0 + wc * 64 + j * 16 + l16;
            int which = n >> 10, h = (n >> 6) & 15, d = n & 63;
            int bh = b * NH + h;
            _Float16 v = (_Float16)acc[i][j][r];
            if (which == 0)
              qout[((size_t)bh * Lq + l) * HD + d] = v;
            else
              kout[((size_t)bh * Lq + l) * HD + d] = v;
          }
        }
      }
    }
  }
}

// ---------- flash attention: swapped-QK in-register P, KEYS=128 tiles ----------
// R14 race-free structure (__syncthreads dbuf), tile widened 64->128 keys:
// halves tile count (35->18 per block), halving barrier/skew/loop overhead
// per unit work. 4 ks-subtiles per tile; V sigma-64-block picked by ks>>1.
// Staging 8x global_load_lds per wave per tile (4 K + 4 V), all L2-resident.
// sigma-permuted V (conflict-free b128), fixed-max softmax, row-sum via
// all-ones MFMA, exp2-domain Q scale.
__global__ __launch_bounds__(256) void attn_f16(const _Float16* __restrict__ qm,
                                                const _Float16* __restrict__ km,
                                                const _Float16* __restrict__ vt,
                                                _Float16* __restrict__ y) {
  __shared__ _Float16 kls[2][KEYS * HD];  // K tiles [key][d], 32 KB
  __shared__ _Float16 vls[2][KEYS * HD];  // V tiles [d][sigma-key], 32 KB

  // XCD swizzle: group same-bh blocks (shared K/V) on one XCD.
  const int i0 = blockIdx.y * (int)gridDim.x + blockIdx.x;  // 17 x 64 = 1088 blocks
  const int logical = (i0 & 7) * (NTQP * Bb * NH / 8) + (i0 >> 3);
  const int bh = logical / NTQP;
  const int px = logical % NTQP;

  const int wid = threadIdx.x >> 6, lane = threadIdx.x & 63;
  const int l16 = lane & 15, lq = lane >> 4;

  const _Float16* qbase = qm + (size_t)bh * Lq * HD;
  const _Float16* kbase = km + (size_t)bh * Lq * HD;
  const _Float16* vbase = vt + (size_t)bh * HD * LqV;
  const int b = bh >> 4, h = bh & 15;

  const _Float16 QSC = (_Float16)(0.125f * 1.44269504f);  // 1/sqrt(64) * log2(e)

  f16x8 ones;
#pragma unroll
  for (int e = 0; e < 8; ++e) ones[e] = (_Float16)1.0f;

  // staging lane constants: 4 K chunks + 4 V chunks per thread per tile
  int rK[4], oK[4];    // K: chunk q=(wid*4+c)*64+lane; row=q>>3 (d-stride 64)
  int rV[4], oV[4];    // V: row=q>>4 (key-stride 128), col=blk*64+swz(c8)
#pragma unroll
  for (int c = 0; c < 4; ++c) {
    int q = (wid * 4 + c) * 64 + lane;
    rK[c] = q >> 3;
    oK[c] = (((q & 7) ^ (rK[c] & 7)) << 3);
    rV[c] = q >> 4;
    int cc = q & 15, blk = cc >> 3, c8 = cc & 7;
    oV[c] = blk * 64 + ((c8 ^ (rV[c] & 7)) << 3);
  }
  _Float16* dK[2][4];
  _Float16* dV[2][4];
#pragma unroll
  for (int bf = 0; bf < 2; ++bf)
#pragma unroll
    for (int c = 0; c < 4; ++c) {
      dK[bf][c] = &kls[bf][(size_t)(wid * 4 + c) * 512];
      dV[bf][c] = &vls[bf][(size_t)(wid * 4 + c) * 512];
    }

  const int nseg = (px == 0) ? 1 : 2;
  for (int seg = 0; seg < nseg; ++seg) {
    const int qt = (px == 0) ? 0 : (seg == 0 ? 33 - px : px);  // 64-row q-tile index
    const int qr0 = qt * 64 + wid * 16;

    int qrow = qr0 + l16; if (qrow > Lq - 1) qrow = Lq - 1;
    f16x8 qf0 = *(const f16x8*)(qbase + (size_t)qrow * HD + lq * 8);
    f16x8 qf1 = *(const f16x8*)(qbase + (size_t)qrow * HD + 32 + lq * 8);
#pragma unroll
    for (int e = 0; e < 8; ++e) {
      qf0[e] *= QSC;
      qf1[e] *= QSC;
    }

    const int irow = qr0 + l16;
    const int kmax = (irow < NMEM) ? (Lq - 1) : (irow < Lq - 1 ? irow : Lq - 1);

    f32x4 o[4];
#pragma unroll
    for (int dt = 0; dt < 4; ++dt) o[dt] = (f32x4){0.f, 0.f, 0.f, 0.f};
    f32x4 ol = (f32x4){0.f, 0.f, 0.f, 0.f};

    // key tiles needed by q-tile qt: ceil((qt+1)*64/128) = (qt+2)>>1 ; qt0 = all
    const int need = (qt + 2) >> 1;
    const int ntiles = (qt == 0) ? NT : (need < NT ? need : NT);

    // incremental per-lane staging pointers (tile 0)
    const _Float16* pk[4];
    const _Float16* pv[4];
#pragma unroll
    for (int c = 0; c < 4; ++c) {
      pk[c] = kbase + (size_t)rK[c] * HD + oK[c];
      pv[c] = vbase + (size_t)rV[c] * LqV + oV[c];
    }

    auto stage_fast = [&](int bf) {
#pragma unroll
      for (int c = 0; c < 4; ++c)
        __builtin_amdgcn_global_load_lds((gvoid_t*)pk[c], (svoid_t*)dK[bf][c], 16, 0, 0);
#pragma unroll
      for (int c = 0; c < 4; ++c)
        __builtin_amdgcn_global_load_lds((gvoid_t*)pv[c], (svoid_t*)dV[bf][c], 16, 0, 0);
#pragma unroll
      for (int c = 0; c < 4; ++c) { pk[c] += KEYS * HD; pv[c] += KEYS; }
    };
    auto stage_clamp = [&](int bf) {
      // tile NT-1 (j0 = 2048): clamp key rows / vT columns into valid range
#pragma unroll
      for (int c = 0; c < 4; ++c) {
        int key = 2048 + rK[c]; if (key > Lq - 1) key = Lq - 1;
        __builtin_amdgcn_global_load_lds((gvoid_t*)(kbase + (size_t)key * HD + oK[c]),
                                         (svoid_t*)dK[bf][c], 16, 0, 0);
      }
#pragma unroll
      for (int c = 0; c < 4; ++c) {
        int kc = 2048 + oV[c]; if (kc + 8 > LqV) kc = LqV - 8;
        __builtin_amdgcn_global_load_lds((gvoid_t*)(vbase + (size_t)rV[c] * LqV + kc),
                                         (svoid_t*)dV[bf][c], 16, 0, 0);
      }
    };

    auto compute = [&](const _Float16* Kl, const _Float16* Vl, int t) {
      const bool fastw = ((t + 1) * KEYS <= qr0);
      const int lim = kmax - t * KEYS;
#pragma unroll
      for (int ks = 0; ks < 4; ++ks) {
        const int r0 = ks * 32 + l16, r1 = r0 + 16;
        f16x8 ka0 = *(const f16x8*)(Kl + r0 * 64 + ((lq ^ (r0 & 7)) << 3));
        f16x8 kb0 = *(const f16x8*)(Kl + r0 * 64 + (((4 + lq) ^ (r0 & 7)) << 3));
        f16x8 ka1 = *(const f16x8*)(Kl + r1 * 64 + ((lq ^ (r1 & 7)) << 3));
        f16x8 kb1 = *(const f16x8*)(Kl + r1 * 64 + (((4 + lq) ^ (r1 & 7)) << 3));
        f32x4 s0 = (f32x4){0.f, 0.f, 0.f, 0.f};
        f32x4 s1 = (f32x4){0.f, 0.f, 0.f, 0.f};
        __builtin_amdgcn_s_setprio(1);
        // SWAPPED operands: lane holds P for q=l16 at keys ks*32 (+16) + lq*4 + r
        s0 = __builtin_amdgcn_mfma_f32_16x16x32_f16(ka0, qf0, s0, 0, 0, 0);
        s0 = __builtin_amdgcn_mfma_f32_16x16x32_f16(kb0, qf1, s0, 0, 0, 0);
        s1 = __builtin_amdgcn_mfma_f32_16x16x32_f16(ka1, qf0, s1, 0, 0, 0);
        s1 = __builtin_amdgcn_mfma_f32_16x16x32_f16(kb1, qf1, s1, 0, 0, 0);
        __builtin_amdgcn_s_setprio(0);

        f16x8 pf;
        if (fastw) {
#pragma unroll
          for (int r = 0; r < 4; ++r) {
            pf[r] = (_Float16)fexp2(s0[r]);
            pf[4 + r] = (_Float16)fexp2(s1[r]);
          }
        } else {
          const int kb = ks * 32 + lq * 4;
#pragma unroll
          for (int r = 0; r < 4; ++r) {
            pf[r] = (kb + r <= lim) ? (_Float16)fexp2(s0[r]) : (_Float16)0.f;
            pf[4 + r] = (kb + 16 + r <= lim) ? (_Float16)fexp2(s1[r]) : (_Float16)0.f;
          }
        }

        __builtin_amdgcn_s_setprio(1);
        ol = __builtin_amdgcn_mfma_f32_16x16x32_f16(pf, ones, ol, 0, 0, 0);
#pragma unroll
        for (int dt = 0; dt < 4; ++dt) {
          const int vr = dt * 16 + l16;
          const int g = (ks & 1) * 4 + lq;
          f16x8 vf = *(const f16x8*)(Vl + vr * KEYS + (ks >> 1) * 64 + ((g ^ (vr & 7)) << 3));
          o[dt] = __builtin_amdgcn_mfma_f32_16x16x32_f16(pf, vf, o[dt], 0, 0, 0);
        }
        __builtin_amdgcn_s_setprio(0);
      }
    };

    stage_fast(0);  // tile 0 (never needs clamping)
    __syncthreads();
    int t = 0;
    for (;;) {
      // even tile -> buffer 0
      {
        int nxt = t + 1;
        if (nxt < ntiles) {
          if (nxt == NT - 1) stage_clamp(1);
          else stage_fast(1);
        }
      }
      compute(kls[0], vls[0], t);
      __syncthreads();
      if (++t >= ntiles) break;
      // odd tile -> buffer 1
      {
        int nxt = t + 1;
        if (nxt < ntiles) {
          if (nxt == NT - 1) stage_clamp(0);
          else stage_fast(0);
        }
      }
      compute(kls[1], vls[1], t);
      __syncthreads();
      if (++t >= ntiles) break;
    }

#pragma unroll
    for (int r = 0; r < 4; ++r) {
      int orow = qr0 + lq * 4 + r;
      if (orow >= Lq) continue;
      float inv = 1.0f / ol[r];
#pragma unroll
      for (int dt = 0; dt < 4; ++dt)
        y[((size_t)(b * Lq + orow)) * Dd + h * HD + dt * 16 + l16] = (_Float16)(o[dt][r] * inv);
    }
  }
}

extern "C" void kernel_launch(void* const* d_in, const int* in_sizes, int n_in,
                              void* d_out, int out_size, void* d_ws, size_t ws_size,
                              hipStream_t stream) {
  (void)in_sizes; (void)n_in; (void)out_size; (void)ws_size;
  const float* x = (const float*)d_in[0];
  const float* W_attn = (const float*)d_in[1];
  const float* W_proj = (const float*)d_in[2];
  float* out = (float*)d_out;

  char* w = (char*)d_ws;
  _Float16* xh  = (_Float16*)(w);                 // 16,842,752 B ; reused as y after QKV
  _Float16* wta = (_Float16*)(w + 16842752);      //  6,291,456 B
  _Float16* wtp = (_Float16*)(w + 23134208);      //  2,097,152 B
  _Float16* qh  = (_Float16*)(w + 25231360);      // 16,842,752 B
  _Float16* kh  = (_Float16*)(w + 42074112);      // 16,842,752 B
  _Float16* vth = (_Float16*)(w + 58916864);      // 16,908,288 B (64x64x2064, end 75,825,152)
  _Float16* yh  = xh;

  // 1. casts
  cast_f16<<<dim3((Mtot * Dd) / 8 / 256), dim3(256), 0, stream>>>(x, xh, (Mtot * Dd) / 8);
  transpose_cast<<<dim3(3 * Dd / 32, Dd / 32), dim3(32, 8), 0, stream>>>(W_attn, wta, Dd, 3 * Dd);
  transpose_cast<<<dim3(Dd / 32, Dd / 32), dim3(32, 8), 0, stream>>>(W_proj, wtp, Dd, Dd);

  // 2. qkv GEMM (M=8224, N=3072, K=1024), scatter epilogue  (24x65=1560 blocks, %8==0)
  gemm_f16<1><<<dim3(3 * Dd / 128, (Mtot + 127) / 128), dim3(256), 0, stream>>>(
      xh, wta, Mtot, 3 * Dd, Dd, nullptr, qh, kh, vth);

  // 3. attention (17 paired q-tile blocks x 64 bh = 1088, %8==0)
  attn_f16<<<dim3(NTQP, Bb * NH), dim3(256), 0, stream>>>(qh, kh, vth, yh);

  // 4. output projection (M=8224, N=1024, K=1024)  (8x65=520 blocks, %8==0)
  gemm_f16<0><<<dim3(Dd / 128, (Mtot + 127) / 128), dim3(256), 0, stream>>>(
      yh, wtp, Mtot, Dd, Dd, out, nullptr, nullptr, nullptr);
}

// Round 17
// 200.304 us; speedup vs baseline: 1.0989x; 1.0989x over previous
//
#include <hip/hip_runtime.h>
#include <hip/hip_bf16.h>
#include <hip/hip_fp16.h>

typedef _Float16 f16x8 __attribute__((ext_vector_type(8)));
typedef _Float16 f16x4 __attribute__((ext_vector_type(4)));
typedef float f32x4 __attribute__((ext_vector_type(4)));

typedef const __attribute__((address_space(1))) void gvoid_t;
typedef __attribute__((address_space(3))) void svoid_t;

constexpr int Bb = 4, Lq = 2056, Dd = 1024, NH = 16, HD = 64, NMEM = 8;
constexpr int Mtot = Bb * Lq;  // 8224
constexpr int KEYS = 64;       // keys per attention LDS tile
constexpr int NT = (Lq + KEYS - 1) / KEYS;  // 33 key tiles
constexpr int NTQP = 17;       // paired q-tile blocks: px=0 -> {0}; px>=1 -> {33-px, px}
constexpr int LqV = 2064;      // padded vT column count (sigma of last tile stays in-bounds)
constexpr int NCAST = (Mtot * Dd / 8) / 256;  // 4112 cast blocks (exact)

__device__ inline float fexp2(float x) {  // v_exp_f32 computes 2^x
  float r;
  asm("v_exp_f32 %0, %1" : "=v"(r) : "v"(x));
  return r;
}

// ---------- fused prep: x cast (blocks 0..NCAST) + W_attn / W_proj ----------
// transpose-casts (remaining blocks). One launch instead of three: cast
// blocks fill the GPU while the small transpose grids run.
__global__ __launch_bounds__(256) void fused_prep(
    const float* __restrict__ x, const float* __restrict__ Wa,
    const float* __restrict__ Wp, _Float16* __restrict__ xh,
    _Float16* __restrict__ wta, _Float16* __restrict__ wtp) {
  const int gb = blockIdx.x;
  const int tid = threadIdx.x;
  if (gb < NCAST) {
    int i = gb * 256 + tid;
    const float4* p = reinterpret_cast<const float4*>(x) + (size_t)i * 2;
    float4 a = p[0], bq = p[1];
    f16x8 o;
    o[0] = (_Float16)a.x; o[1] = (_Float16)a.y; o[2] = (_Float16)a.z; o[3] = (_Float16)a.w;
    o[4] = (_Float16)bq.x; o[5] = (_Float16)bq.y; o[6] = (_Float16)bq.z; o[7] = (_Float16)bq.w;
    *(reinterpret_cast<f16x8*>(xh) + i) = o;
    return;
  }
  __shared__ float t[32][33];
  const float* in;
  _Float16* out;
  int rows = Dd, cols, bx, by;
  if (gb < NCAST + 3072) {  // W_attn: 96 x 32 transpose blocks
    int g = gb - NCAST;
    bx = g % 96; by = g / 96;
    in = Wa; out = wta; cols = 3 * Dd;
  } else {                  // W_proj: 32 x 32 transpose blocks
    int g = gb - NCAST - 3072;
    bx = g & 31; by = g >> 5;
    in = Wp; out = wtp; cols = Dd;
  }
  const int tx = tid & 31, ty = tid >> 5;
  const int c0 = bx * 32, r0 = by * 32;
#pragma unroll
  for (int i = 0; i < 4; ++i)
    t[ty + i * 8][tx] = in[(size_t)(r0 + ty + i * 8) * cols + c0 + tx];
  __syncthreads();
#pragma unroll
  for (int i = 0; i < 4; ++i)
    out[(size_t)(c0 + ty + i * 8) * rows + r0 + tx] = (_Float16)t[tx][ty + i * 8];
}

// ---------- GEMM: C(MxN) = A(MxK) * Bt(NxK)^T, fp16 in, fp32 acc ----------
// Double-buffered global_load_lds prefetch; XCD-aware bijective block swizzle.
// EPI==1 scatters q/k and sigma-permuted vT (key k -> column (k&~63)+sigma(k&63))
// so attention's PV B-fragment is one contiguous 16B LDS chunk.
template <int EPI>
__global__ __launch_bounds__(256) void gemm_f16(
    const _Float16* __restrict__ A, const _Float16* __restrict__ Bt,
    int M, int N, int Kd, float* __restrict__ Cf,
    _Float16* __restrict__ qout, _Float16* __restrict__ kout, _Float16* __restrict__ vtout) {
  constexpr int BM = 128, BN = 128, BK = 64;
  __shared__ _Float16 smem[2][2 * BM * BK];  // [dbuf][A tile | B tile] = 64 KB
  const int tid = threadIdx.x;
  const int wid = tid >> 6, lane = tid & 63;
  const int wr = wid >> 1, wc = wid & 1;
  const int l16 = lane & 15, lq = lane >> 4;

  const int gx = gridDim.x;
  const int nwg = gx * gridDim.y;
  const int i0 = blockIdx.y * gx + blockIdx.x;
  const int cpx = nwg >> 3;
  const int logical = (i0 & 7) * cpx + (i0 >> 3);
  const int m0 = (logical / gx) * BM, n0 = (logical % gx) * BN;

  f32x4 acc[4][4];
#pragma unroll
  for (int i = 0; i < 4; ++i)
#pragma unroll
    for (int j = 0; j < 4; ++j) acc[i][j] = (f32x4){0.f, 0.f, 0.f, 0.f};

  auto stage = [&](int sb, int kt) {
    const size_t kbase = (size_t)kt * BK;
    _Float16* sm = smem[sb];
#pragma unroll
    for (int c = 0; c < 4; ++c) {
      int q = wid * 256 + c * 64 + lane;
      int r = q >> 3, cc = q & 7;
      int gr = m0 + r; gr = gr < M ? gr : M - 1;
      const _Float16* src = A + (size_t)gr * Kd + kbase + ((cc ^ (r & 7)) << 3);
      __builtin_amdgcn_global_load_lds((gvoid_t*)src,
          (svoid_t*)(sm + (size_t)(wid * 256 + c * 64) * 8), 16, 0, 0);
    }
#pragma unroll
    for (int c = 0; c < 4; ++c) {
      int q = wid * 256 + c * 64 + lane;
      int r = q >> 3, cc = q & 7;
      const _Float16* src = Bt + (size_t)(n0 + r) * Kd + kbase + ((cc ^ (r & 7)) << 3);
      __builtin_amdgcn_global_load_lds((gvoid_t*)src,
          (svoid_t*)(sm + BM * BK + (size_t)(wid * 256 + c * 64) * 8), 16, 0, 0);
    }
  };

  const int KT = Kd / BK;
  stage(0, 0);
  __syncthreads();
  int sbuf = 0;
  for (int kt = 0; kt < KT; ++kt) {
    if (kt + 1 < KT) stage(sbuf ^ 1, kt + 1);  // prefetch overlaps compute
    const _Float16* sm = smem[sbuf];
#pragma unroll
    for (int kk = 0; kk < 2; ++kk) {
      f16x8 af[4], bfr[4];
#pragma unroll
      for (int i = 0; i < 4; ++i) {
        int r = wr * 64 + i * 16 + l16;
        int off = r * 64 + (((kk * 4 + lq) ^ (r & 7)) << 3);
        af[i] = *(const f16x8*)(sm + off);
      }
#pragma unroll
      for (int j = 0; j < 4; ++j) {
        int r = wc * 64 + j * 16 + l16;
        int off = BM * BK + r * 64 + (((kk * 4 + lq) ^ (r & 7)) << 3);
        bfr[j] = *(const f16x8*)(sm + off);
      }
#pragma unroll
      for (int i = 0; i < 4; ++i)
#pragma unroll
        for (int j = 0; j < 4; ++j)
          acc[i][j] = __builtin_amdgcn_mfma_f32_16x16x32_f16(af[i], bfr[j], acc[i][j], 0, 0, 0);
    }
    __syncthreads();
    sbuf ^= 1;
  }

  // epilogue: D row = (lane>>4)*4 + reg, col = lane&15
  if (EPI == 1 && n0 >= 2 * Dd) {
    // v block: sigma-permuted columns; pack 4 consecutive l into one 8B store
#pragma unroll
    for (int i = 0; i < 4; ++i) {
      int mb = m0 + wr * 64 + i * 16 + lq * 4;
      if (mb >= M) continue;
      int b = mb / Lq, l = mb - b * Lq;
#pragma unroll
      for (int j = 0; j < 4; ++j) {
        int n = n0 + wc * 64 + j * 16 + l16;
        int h = (n >> 6) & 15, d = n & 63;
        if (l + 4 <= Lq) {
          int kk = l & 63;
          int ks = kk >> 5, rem = kk & 31, half = rem >> 4, idx = rem & 15;
          int col = (l & ~63) + (ks * 4 + (idx >> 2)) * 8 + half * 4;  // idx&3 == 0
          f16x4 pk;
          pk[0] = (_Float16)acc[i][j][0]; pk[1] = (_Float16)acc[i][j][1];
          pk[2] = (_Float16)acc[i][j][2]; pk[3] = (_Float16)acc[i][j][3];
          *(f16x4*)(vtout + ((size_t)(b * NH + h) * HD + d) * LqV + col) = pk;
        } else {
#pragma unroll
          for (int r = 0; r < 4; ++r) {
            int m = mb + r;
            if (m >= M) continue;
            int b2 = m / Lq, l2 = m - b2 * Lq;
            int kk = l2 & 63;
            int ks = kk >> 5, rem = kk & 31, half = rem >> 4, idx = rem & 15;
            int col = (l2 & ~63) + (ks * 4 + (idx >> 2)) * 8 + half * 4 + (idx & 3);
            vtout[((size_t)(b2 * NH + h) * HD + d) * LqV + col] = (_Float16)acc[i][j][r];
          }
        }
      }
    }
  } else {
#pragma unroll
    for (int i = 0; i < 4; ++i) {
#pragma unroll
      for (int r = 0; r < 4; ++r) {
        int m = m0 + wr * 64 + i * 16 + lq * 4 + r;
        if (m >= M) continue;
        if (EPI == 0) {
#pragma unroll
          for (int j = 0; j < 4; ++j) {
            int n = n0 + wc * 64 + j * 16 + l16;
            Cf[(size_t)m * N + n] = acc[i][j][r];
          }
        } else {
          int b = m / Lq, l = m - b * Lq;
#pragma unroll
          for (int j = 0; j < 4; ++j) {
            int n = n0 + wc * 64 + j * 16 + l16;
            int which = n >> 10, h = (n >> 6) & 15, d = n & 63;
            int bh = b * NH + h;
            _Float16 v = (_Float16)acc[i][j][r];
            if (which == 0)
              qout[((size_t)bh * Lq + l) * HD + d] = v;
            else
              kout[((size_t)bh * Lq + l) * HD + d] = v;
          }
        }
      }
    }
  }
}

// ---------- flash attention: swapped-QK in-register P, paired q-tiles ----------
// (R14 configuration — best measured: 83.0 us, zero bank conflicts.)
// V read mirrors K: sigma-permuted vT makes each PV B-fragment one contiguous
// XOR-swizzled ds_read_b128 (conflict-free). Staging uses incremental
// per-lane pointers (+8KB K, +128B V per tile); only tile 32 needs the
// clamped variant. Tile loop manually 2x-unrolled for static LDS bases.
// Fixed-max softmax; row-sum via all-ones MFMA; exp2-domain Q scale.
__global__ __launch_bounds__(256) void attn_f16(const _Float16* __restrict__ qm,
                                                const _Float16* __restrict__ km,
                                                const _Float16* __restrict__ vt,
                                                _Float16* __restrict__ y) {
  __shared__ _Float16 kls[2][KEYS * HD];  // K tiles [key][d], 16 KB
  __shared__ _Float16 vls[2][KEYS * HD];  // V tiles [d][sigma-key], 16 KB

  // XCD swizzle: group same-bh blocks (shared K/V) on one XCD.
  const int i0 = blockIdx.y * (int)gridDim.x + blockIdx.x;  // 17 x 64 = 1088 blocks
  const int logical = (i0 & 7) * (NTQP * Bb * NH / 8) + (i0 >> 3);
  const int bh = logical / NTQP;
  const int px = logical % NTQP;

  const int wid = threadIdx.x >> 6, lane = threadIdx.x & 63;
  const int l16 = lane & 15, lq = lane >> 4;

  const _Float16* qbase = qm + (size_t)bh * Lq * HD;
  const _Float16* kbase = km + (size_t)bh * Lq * HD;
  const _Float16* vbase = vt + (size_t)bh * HD * LqV;
  const int b = bh >> 4, h = bh & 15;

  const _Float16 QSC = (_Float16)(0.125f * 1.44269504f);  // 1/sqrt(64) * log2(e)

  f16x8 ones;
#pragma unroll
  for (int e = 0; e < 8; ++e) ones[e] = (_Float16)1.0f;

  // staging lane constants (shared by both segments)
  const int qA = (wid * 2 + 0) * 64 + lane, qB = (wid * 2 + 1) * 64 + lane;
  const int rA = qA >> 3, cA = qA & 7;
  const int rB = qB >> 3, cB = qB & 7;
  const int ofA = (cA ^ (rA & 7)) << 3;
  const int ofB = (cB ^ (rB & 7)) << 3;
  _Float16* dKA0 = &kls[0][(wid * 2 + 0) * 512]; _Float16* dKB0 = &kls[0][(wid * 2 + 1) * 512];
  _Float16* dKA1 = &kls[1][(wid * 2 + 0) * 512]; _Float16* dKB1 = &kls[1][(wid * 2 + 1) * 512];
  _Float16* dVA0 = &vls[0][(wid * 2 + 0) * 512]; _Float16* dVB0 = &vls[0][(wid * 2 + 1) * 512];
  _Float16* dVA1 = &vls[1][(wid * 2 + 0) * 512]; _Float16* dVB1 = &vls[1][(wid * 2 + 1) * 512];

  const int nseg = (px == 0) ? 1 : 2;
  for (int seg = 0; seg < nseg; ++seg) {
    const int qt = (px == 0) ? 0 : (seg == 0 ? NT - px : px);  // long segment first
    const int qr0 = qt * 64 + wid * 16;

    int qrow = qr0 + l16; if (qrow > Lq - 1) qrow = Lq - 1;
    f16x8 qf0 = *(const f16x8*)(qbase + (size_t)qrow * HD + lq * 8);
    f16x8 qf1 = *(const f16x8*)(qbase + (size_t)qrow * HD + 32 + lq * 8);
#pragma unroll
    for (int e = 0; e < 8; ++e) {
      qf0[e] *= QSC;
      qf1[e] *= QSC;
    }

    const int irow = qr0 + l16;
    const int kmax = (irow < NMEM) ? (Lq - 1) : (irow < Lq - 1 ? irow : Lq - 1);

    f32x4 o[4];
#pragma unroll
    for (int dt = 0; dt < 4; ++dt) o[dt] = (f32x4){0.f, 0.f, 0.f, 0.f};
    f32x4 ol = (f32x4){0.f, 0.f, 0.f, 0.f};

    const int ntiles = (qt == 0) ? NT : (qt + 1 < NT ? qt + 1 : NT);

    // incremental per-lane staging pointers (tile 0)
    const _Float16* pkA = kbase + (size_t)rA * HD + ofA;
    const _Float16* pkB = kbase + (size_t)rB * HD + ofB;
    const _Float16* pvA = vbase + (size_t)rA * LqV + ofA;
    const _Float16* pvB = vbase + (size_t)rB * LqV + ofB;

    auto stage_fast = [&](_Float16* dK0, _Float16* dK1, _Float16* dV0, _Float16* dV1) {
      __builtin_amdgcn_global_load_lds((gvoid_t*)pkA, (svoid_t*)dK0, 16, 0, 0);
      __builtin_amdgcn_global_load_lds((gvoid_t*)pkB, (svoid_t*)dK1, 16, 0, 0);
      __builtin_amdgcn_global_load_lds((gvoid_t*)pvA, (svoid_t*)dV0, 16, 0, 0);
      __builtin_amdgcn_global_load_lds((gvoid_t*)pvB, (svoid_t*)dV1, 16, 0, 0);
      pkA += KEYS * HD; pkB += KEYS * HD; pvA += KEYS; pvB += KEYS;
    };
    auto stage_clamp = [&](_Float16* dK0, _Float16* dK1, _Float16* dV0, _Float16* dV1) {
      // tile NT-1 (j0 = 2048): clamp key rows / vT columns into valid range
      int keyA = 2048 + rA; if (keyA > Lq - 1) keyA = Lq - 1;
      int keyB = 2048 + rB; if (keyB > Lq - 1) keyB = Lq - 1;
      __builtin_amdgcn_global_load_lds((gvoid_t*)(kbase + (size_t)keyA * HD + ofA),
                                       (svoid_t*)dK0, 16, 0, 0);
      __builtin_amdgcn_global_load_lds((gvoid_t*)(kbase + (size_t)keyB * HD + ofB),
                                       (svoid_t*)dK1, 16, 0, 0);
      int kcA = 2048 + ofA; if (kcA + 8 > LqV) kcA = LqV - 8;
      int kcB = 2048 + ofB; if (kcB + 8 > LqV) kcB = LqV - 8;
      __builtin_amdgcn_global_load_lds((gvoid_t*)(vbase + (size_t)rA * LqV + kcA),
                                       (svoid_t*)dV0, 16, 0, 0);
      __builtin_amdgcn_global_load_lds((gvoid_t*)(vbase + (size_t)rB * LqV + kcB),
                                       (svoid_t*)dV1, 16, 0, 0);
    };

    auto compute = [&](const _Float16* Kl, const _Float16* Vl, int t) {
      const bool fastw = ((t + 1) * KEYS <= qr0);
      const int lim = kmax - t * KEYS;
#pragma unroll
      for (int ks = 0; ks < 2; ++ks) {
        const int r0 = ks * 32 + l16, r1 = r0 + 16;
        f16x8 ka0 = *(const f16x8*)(Kl + r0 * 64 + ((lq ^ (r0 & 7)) << 3));
        f16x8 kb0 = *(const f16x8*)(Kl + r0 * 64 + (((4 + lq) ^ (r0 & 7)) << 3));
        f16x8 ka1 = *(const f16x8*)(Kl + r1 * 64 + ((lq ^ (r1 & 7)) << 3));
        f16x8 kb1 = *(const f16x8*)(Kl + r1 * 64 + (((4 + lq) ^ (r1 & 7)) << 3));
        f32x4 s0 = (f32x4){0.f, 0.f, 0.f, 0.f};
        f32x4 s1 = (f32x4){0.f, 0.f, 0.f, 0.f};
        __builtin_amdgcn_s_setprio(1);
        // SWAPPED operands: lane holds P for q=l16 at keys (ks*32|+16) + lq*4 + r
        s0 = __builtin_amdgcn_mfma_f32_16x16x32_f16(ka0, qf0, s0, 0, 0, 0);
        s0 = __builtin_amdgcn_mfma_f32_16x16x32_f16(kb0, qf1, s0, 0, 0, 0);
        s1 = __builtin_amdgcn_mfma_f32_16x16x32_f16(ka1, qf0, s1, 0, 0, 0);
        s1 = __builtin_amdgcn_mfma_f32_16x16x32_f16(kb1, qf1, s1, 0, 0, 0);
        __builtin_amdgcn_s_setprio(0);

        f16x8 pf;
        if (fastw) {
#pragma unroll
          for (int r = 0; r < 4; ++r) {
            pf[r] = (_Float16)fexp2(s0[r]);
            pf[4 + r] = (_Float16)fexp2(s1[r]);
          }
        } else {
          const int kb = ks * 32 + lq * 4;
#pragma unroll
          for (int r = 0; r < 4; ++r) {
            pf[r] = (kb + r <= lim) ? (_Float16)fexp2(s0[r]) : (_Float16)0.f;
            pf[4 + r] = (kb + 16 + r <= lim) ? (_Float16)fexp2(s1[r]) : (_Float16)0.f;
          }
        }

        __builtin_amdgcn_s_setprio(1);
        ol = __builtin_amdgcn_mfma_f32_16x16x32_f16(pf, ones, ol, 0, 0, 0);
#pragma unroll
        for (int dt = 0; dt < 4; ++dt) {
          const int vr = dt * 16 + l16;
          const int g = ks * 4 + lq;
          f16x8 vf = *(const f16x8*)(Vl + vr * 64 + ((g ^ (vr & 7)) << 3));
          o[dt] = __builtin_amdgcn_mfma_f32_16x16x32_f16(pf, vf, o[dt], 0, 0, 0);
        }
        __builtin_amdgcn_s_setprio(0);
      }
    };

    stage_fast(dKA0, dKB0, dVA0, dVB0);  // tile 0 (never needs clamping)
    __syncthreads();
    int t = 0;
    for (;;) {
      // even tile -> buffer 0
      {
        int nxt = t + 1;
        if (nxt < ntiles) {
          if (nxt == NT - 1) stage_clamp(dKA1, dKB1, dVA1, dVB1);
          else stage_fast(dKA1, dKB1, dVA1, dVB1);
        }
      }
      compute(kls[0], vls[0], t);
      __syncthreads();
      if (++t >= ntiles) break;
      // odd tile -> buffer 1
      {
        int nxt = t + 1;
        if (nxt < ntiles) {
          if (nxt == NT - 1) stage_clamp(dKA0, dKB0, dVA0, dVB0);
          else stage_fast(dKA0, dKB0, dVA0, dVB0);
        }
      }
      compute(kls[1], vls[1], t);
      __syncthreads();
      if (++t >= ntiles) break;
    }

#pragma unroll
    for (int r = 0; r < 4; ++r) {
      int orow = qr0 + lq * 4 + r;
      if (orow >= Lq) continue;
      float inv = 1.0f / ol[r];
#pragma unroll
      for (int dt = 0; dt < 4; ++dt)
        y[((size_t)(b * Lq + orow)) * Dd + h * HD + dt * 16 + l16] = (_Float16)(o[dt][r] * inv);
    }
  }
}

extern "C" void kernel_launch(void* const* d_in, const int* in_sizes, int n_in,
                              void* d_out, int out_size, void* d_ws, size_t ws_size,
                              hipStream_t stream) {
  (void)in_sizes; (void)n_in; (void)out_size; (void)ws_size;
  const float* x = (const float*)d_in[0];
  const float* W_attn = (const float*)d_in[1];
  const float* W_proj = (const float*)d_in[2];
  float* out = (float*)d_out;

  char* w = (char*)d_ws;
  _Float16* xh  = (_Float16*)(w);                 // 16,842,752 B ; reused as y after QKV
  _Float16* wta = (_Float16*)(w + 16842752);      //  6,291,456 B
  _Float16* wtp = (_Float16*)(w + 23134208);      //  2,097,152 B
  _Float16* qh  = (_Float16*)(w + 25231360);      // 16,842,752 B
  _Float16* kh  = (_Float16*)(w + 42074112);      // 16,842,752 B
  _Float16* vth = (_Float16*)(w + 58916864);      // 16,908,288 B (64x64x2064, end 75,825,152)
  _Float16* yh  = xh;

  // 1. fused prep: x cast + W_attn/W_proj transpose-casts (4112+3072+1024 blocks)
  fused_prep<<<dim3(NCAST + 3072 + 1024), dim3(256), 0, stream>>>(
      x, W_attn, W_proj, xh, wta, wtp);

  // 2. qkv GEMM (M=8224, N=3072, K=1024), scatter epilogue  (24x65=1560 blocks, %8==0)
  gemm_f16<1><<<dim3(3 * Dd / 128, (Mtot + 127) / 128), dim3(256), 0, stream>>>(
      xh, wta, Mtot, 3 * Dd, Dd, nullptr, qh, kh, vth);

  // 3. attention (17 paired q-tile blocks x 64 bh = 1088, %8==0)
  attn_f16<<<dim3(NTQP, Bb * NH), dim3(256), 0, stream>>>(qh, kh, vth, yh);

  // 4. output projection (M=8224, N=1024, K=1024)  (8x65=520 blocks, %8==0)
  gemm_f16<0><<<dim3(Dd / 128, (Mtot + 127) / 128), dim3(256), 0, stream>>>(
      yh, wtp, Mtot, Dd, Dd, out, nullptr, nullptr, nullptr);
}